// Round 5
// baseline (432.558 us; speedup 1.0000x reference)
//
#include <hip/hip_runtime.h>

#define T_LEN 32768
#define ADIM  512
#define NDEC  1024
#define KTAPS 31

// workspace float offsets
#define WS_BASE 0        // 512   : dec_proj[a] + conv-bias proj        (k0->k1)
#define WS_G    512      // 15872 : G[k][a] = sum_c conv_w[c,k]*W_att   (k0->k1)
#define WS_CREP 0        // 16384 : 32 replicated c-accumulators — ALIASES BASE+G,
                         //         zeroed by k2a (after k1 done), used by k3 finalize
#define WS_SARR 16384    // 32768 : partial e sums (k1, atomic) then sv (k2a overwrite)
#define WS_BMAX 49152    // 64    : per-k2a-block online max
#define WS_BSUM 49216    // 64    : per-k2a-block online sumexp
#define WS_SSUM 49280    // 1     : sum of clipped u
#define WS_CTR  49284    // 1     : uint finalize counter for k3 (zeroed by k0)
#define WS_U    50432    // 32768 : u[t]

__device__ __forceinline__ float fast_tanh(float x) {
    // tanh(x) = 1 - 2/(exp(2x)+1); ~1e-7 abs err vs 3.5e-4 threshold
    float e = __expf(2.0f * x);
    return 1.0f - 2.0f * __builtin_amdgcn_rcpf(e + 1.0f);
}

__device__ __forceinline__ float uniform_f(float v) {
    return __uint_as_float(__builtin_amdgcn_readfirstlane(__float_as_uint(v)));
}

// ---------------- K0: dec_proj+bias -> base[512]; G[31][512]; zero SARR/SSUM/CTR ------
__global__ __launch_bounds__(256) void k0_prep(
        const float* __restrict__ dec_z, const float* __restrict__ conv_w,
        const float* __restrict__ conv_b, const float* __restrict__ W_att,
        const float* __restrict__ W_dec, float* __restrict__ ws) {
    int b = blockIdx.x, tid = threadIdx.x;
    int lane = tid & 63, wave = tid >> 6;
    if (b < 64) {
        // 8 a's per block, wave handles 2 (64-lane dot over 1024)
        for (int s = 0; s < 2; ++s) {
            int a = b * 8 + wave * 2 + s;
            float sum = 0.f;
            #pragma unroll
            for (int i = 0; i < 16; ++i)
                sum += W_dec[a * NDEC + i * 64 + lane] * dec_z[i * 64 + lane];
            #pragma unroll
            for (int off = 32; off > 0; off >>= 1) sum += __shfl_xor(sum, off);
            if (lane == 0) {
                float bias = 0.f;
                #pragma unroll
                for (int c = 0; c < 32; ++c) bias += conv_b[c] * W_att[a * 32 + c];
                ws[WS_BASE + a] = sum + bias;
            }
        }
    } else if (b < 64 + KTAPS) {
        int k = b - 64;
        for (int r = 0; r < 2; ++r) {
            int a = tid + r * 256;
            float g = 0.f;
            #pragma unroll
            for (int c = 0; c < 32; ++c) g += conv_w[c * KTAPS + k] * W_att[a * 32 + c];
            ws[WS_G + k * ADIM + a] = g;
        }
    } else if (b == 95) {
        if (tid == 0) {
            ws[WS_SSUM] = 0.f;
            ((unsigned int*)ws)[WS_CTR] = 0u;
        }
    } else {
        // blocks 96..127: zero SARR (32 blocks x 256 thr x 4 floats = 32768)
        int idx = (b - 96) * 1024 + tid * 4;
        *(float4*)(ws + WS_SARR + idx) = make_float4(0.f, 0.f, 0.f, 0.f);
    }
}

// ---------------- K1: partial energies, a-split ---------------------------------------
// 2048 blocks x 256 thr (4 waves). half = bid&1 selects a in [256h,256h+256);
// t-group = bid>>1 covers 32 t's (8 per wave). G-half staged in LDS (~31 KB ->
// 5 blocks/CU = 20 waves/CU). Lane owns float4 of a; partial e added to SARR (2-way).
__global__ __launch_bounds__(256, 5) void k1_energy(
        const float* __restrict__ att_prev, const float* __restrict__ pre,
        const float* __restrict__ W_g, float* __restrict__ ws) {
    __shared__ float Gs[KTAPS * 256];   // 31744 B
    __shared__ float ap_s[62];
    int tid = threadIdx.x, lane = tid & 63, wave = tid >> 6;
    int half = blockIdx.x & 1;
    int t0 = (blockIdx.x >> 1) * 32;

    // stage G-half: 7936 floats = 1984 float4 (row k has 64 float4 at stride-512 src)
    #pragma unroll
    for (int i = 0; i < 8; ++i) {
        int idx = tid + i * 256;
        if (idx < 1984) {
            int k = idx >> 6, col = idx & 63;
            ((float4*)Gs)[idx] = *(const float4*)(ws + WS_G + k * ADIM + half * 256 + col * 4);
        }
    }
    // stage att_prev window [t0-15, t0+46]
    if (tid < 62) {
        int g = t0 - 15 + tid;
        ap_s[tid] = (g >= 0 && g < T_LEN) ? att_prev[g] : 0.f;
    }
    __syncthreads();

    int tb_local = wave * 8;
    int tb = t0 + tb_local;

    // wave-uniform ap window -> SGPRs (j+k in [0,37])
    float ap_u[38];
    #pragma unroll
    for (int i = 0; i < 38; ++i) ap_u[i] = uniform_f(ap_s[tb_local + i]);

    int aa = 4 * lane;                       // a-local in [0,256)
    float4 base = *(const float4*)(ws + WS_BASE + half * 256 + aa);
    float4 wg   = *(const float4*)(W_g + half * 256 + aa);

    float4 p[8];
    #pragma unroll
    for (int j = 0; j < 8; ++j)
        p[j] = *(const float4*)(pre + (size_t)(tb + j) * ADIM + half * 256 + aa);

    float4 acc[8];
    #pragma unroll
    for (int j = 0; j < 8; ++j) acc[j] = base;

    #pragma unroll
    for (int k = 0; k < KTAPS; ++k) {
        float4 g = *(const float4*)(&Gs[k * 256 + aa]);
        #pragma unroll
        for (int j = 0; j < 8; ++j) {
            float apv = ap_u[j + k];
            acc[j].x = fmaf(apv, g.x, acc[j].x);
            acc[j].y = fmaf(apv, g.y, acc[j].y);
            acc[j].z = fmaf(apv, g.z, acc[j].z);
            acc[j].w = fmaf(apv, g.w, acc[j].w);
        }
    }
    #pragma unroll
    for (int j = 0; j < 8; ++j) {
        float s;
        s = fast_tanh(p[j].x + acc[j].x) * wg.x;
        s = fmaf(fast_tanh(p[j].y + acc[j].y), wg.y, s);
        s = fmaf(fast_tanh(p[j].z + acc[j].z), wg.z, s);
        s = fmaf(fast_tanh(p[j].w + acc[j].w), wg.w, s);
        #pragma unroll
        for (int off = 32; off > 0; off >>= 1) s += __shfl_xor(s, off);
        if (lane == 0) atomicAdd(&ws[WS_SARR + tb + j], s);   // 2 contenders (halves)
    }
}

// ---------------- K2a: sv[t]; per-block online (M,Z); zero c-replicas -----------------
// 64 blocks x 256 thr, 512 t's each.
__global__ __launch_bounds__(256) void k2a_stats(
        const float* __restrict__ mask, const float* __restrict__ b_g,
        float* __restrict__ ws) {
    __shared__ float wm[4], wz[4];
    int tid = threadIdx.x, lane = tid & 63, wave = tid >> 6;
    // zero replicas: 64 blocks x 256 = 16384 floats (region dead after k1)
    ws[WS_CREP + blockIdx.x * 256 + tid] = 0.f;

    float bg = b_g[0];
    int t = blockIdx.x * 512 + tid;
    float sv0 = 2.0f * (ws[WS_SARR + t] + bg + mask[t]);
    float sv1 = 2.0f * (ws[WS_SARR + t + 256] + bg + mask[t + 256]);
    ws[WS_SARR + t] = sv0;
    ws[WS_SARR + t + 256] = sv1;
    float M = fmaxf(sv0, sv1);
    float Z = __expf(sv0 - M) + __expf(sv1 - M);
    #pragma unroll
    for (int off = 32; off > 0; off >>= 1) {
        float Mo = __shfl_xor(M, off), Zo = __shfl_xor(Z, off);
        float mn = fmaxf(M, Mo);
        Z = Z * __expf(M - mn) + Zo * __expf(Mo - mn);
        M = mn;
    }
    if (lane == 0) { wm[wave] = M; wz[wave] = Z; }
    __syncthreads();
    if (tid == 0) {
        float Mg = wm[0], Zg = wz[0];
        #pragma unroll
        for (int w = 1; w < 4; ++w) {
            float mn = fmaxf(Mg, wm[w]);
            Zg = Zg * __expf(Mg - mn) + wz[w] * __expf(wm[w] - mn);
            Mg = mn;
        }
        ws[WS_BMAX + blockIdx.x] = Mg;
        ws[WS_BSUM + blockIdx.x] = Zg;
    }
}

// ---------------- K2b: combine 64 (M,Z); u[t]; atomic S -------------------------------
// 128 blocks x 256 thr. Every wave redundantly butterfly-combines the 64 pairs.
__global__ __launch_bounds__(256) void k2b_weights(
        const float* __restrict__ att_prev, float* __restrict__ ws) {
    __shared__ float wsum[4];
    int tid = threadIdx.x, lane = tid & 63, wave = tid >> 6;
    float M = ws[WS_BMAX + lane], Z = ws[WS_BSUM + lane];
    #pragma unroll
    for (int off = 32; off > 0; off >>= 1) {
        float Mo = __shfl_xor(M, off), Zo = __shfl_xor(Z, off);
        float mn = fmaxf(M, Mo);
        Z = Z * __expf(M - mn) + Zo * __expf(Mo - mn);
        M = mn;
    }
    float invZ = 1.0f / Z;
    int t = blockIdx.x * 256 + tid;
    float pair = att_prev[t] + ((t > 0) ? att_prev[t - 1] : 0.f);
    float u = fmaxf(pair * __expf(ws[WS_SARR + t] - M) * invZ, 1e-6f);
    ws[WS_U + t] = u;
    float s = u;
    #pragma unroll
    for (int off = 32; off > 0; off >>= 1) s += __shfl_xor(s, off);
    if (lane == 0) wsum[wave] = s;
    __syncthreads();
    if (tid == 0) atomicAdd(&ws[WS_SSUM], wsum[0] + wsum[1] + wsum[2] + wsum[3]);
}

// ---------------- K3: w -> out[512+]; c partials -> 32 replicas; last block finalizes -
// 1024 blocks x 512 thr. 4 teams of 128; team covers 8 t's x 512 a's.
__global__ __launch_bounds__(512) void k3_context(
        const float* __restrict__ enc_h, float* __restrict__ ws,
        float* __restrict__ out) {
    __shared__ float cbuf[4 * 512];
    __shared__ int is_last;
    int tid = threadIdx.x;
    int team = tid >> 7, l = tid & 127;
    int a4 = 4 * l;
    int t0 = blockIdx.x * 32;
    float invS = 1.0f / ws[WS_SSUM];
    if (tid < 32) out[512 + t0 + tid] = ws[WS_U + t0 + tid] * invS;
    int tbase = t0 + team * 8;
    float4 acc = make_float4(0.f, 0.f, 0.f, 0.f);
    #pragma unroll
    for (int i = 0; i < 8; ++i) {
        int t = tbase + i;
        float wt = ws[WS_U + t] * invS;
        float4 e = *(const float4*)(enc_h + (size_t)t * ADIM + a4);
        acc.x = fmaf(wt, e.x, acc.x);
        acc.y = fmaf(wt, e.y, acc.y);
        acc.z = fmaf(wt, e.z, acc.z);
        acc.w = fmaf(wt, e.w, acc.w);
    }
    if (team != 0) *(float4*)&cbuf[team * 512 + a4] = acc;
    __syncthreads();
    if (team == 0) {
        float4 b1 = *(const float4*)&cbuf[1 * 512 + a4];
        float4 b2 = *(const float4*)&cbuf[2 * 512 + a4];
        float4 b3 = *(const float4*)&cbuf[3 * 512 + a4];
        float* rep = ws + WS_CREP + (blockIdx.x & 31) * 512;
        atomicAdd(&rep[a4 + 0], acc.x + b1.x + b2.x + b3.x);
        atomicAdd(&rep[a4 + 1], acc.y + b1.y + b2.y + b3.y);
        atomicAdd(&rep[a4 + 2], acc.z + b1.z + b2.z + b3.z);
        atomicAdd(&rep[a4 + 3], acc.w + b1.w + b2.w + b3.w);
        __threadfence();
    }
    __syncthreads();
    if (tid == 0) {
        unsigned int old = atomicAdd(&((unsigned int*)ws)[WS_CTR], 1u);
        is_last = (old == gridDim.x - 1);
    }
    __syncthreads();
    if (is_last) {
        __threadfence();
        float accf = 0.f;
        #pragma unroll
        for (int r = 0; r < 32; ++r) accf += ws[WS_CREP + r * 512 + tid];
        out[tid] = accf;
    }
}

extern "C" void kernel_launch(void* const* d_in, const int* in_sizes, int n_in,
                              void* d_out, int out_size, void* d_ws, size_t ws_size,
                              hipStream_t stream) {
    const float* dec_z    = (const float*)d_in[0];
    const float* att_prev = (const float*)d_in[1];
    const float* pre      = (const float*)d_in[2];
    const float* enc_h    = (const float*)d_in[3];
    const float* mask     = (const float*)d_in[4];
    const float* conv_w   = (const float*)d_in[5];
    const float* conv_b   = (const float*)d_in[6];
    const float* W_att    = (const float*)d_in[7];
    const float* W_dec    = (const float*)d_in[8];
    const float* W_g      = (const float*)d_in[9];
    const float* b_g      = (const float*)d_in[10];
    float* out = (float*)d_out;
    float* ws  = (float*)d_ws;

    k0_prep    <<<128,  256, 0, stream>>>(dec_z, conv_w, conv_b, W_att, W_dec, ws);
    k1_energy  <<<2048, 256, 0, stream>>>(att_prev, pre, W_g, ws);
    k2a_stats  <<<64,   256, 0, stream>>>(mask, b_g, ws);
    k2b_weights<<<128,  256, 0, stream>>>(att_prev, ws);
    k3_context <<<1024, 512, 0, stream>>>(enc_h, ws, out);
}

// Round 6
// 274.831 us; speedup vs baseline: 1.5739x; 1.5739x over previous
//
#include <hip/hip_runtime.h>

#define T_LEN 32768
#define ADIM  512
#define NDEC  1024
#define KTAPS 31

// workspace float offsets
#define WS_BASE 0        // 512   : dec_proj[a] + conv-bias proj        (k0->k1)
#define WS_G    512      // 15872 : G[k][a] = sum_c conv_w[c,k]*W_att   (k0->k1)
#define WS_CREP 0        // 16384 : 32 replicated c-accumulators — ALIASES BASE+G,
                         //         zeroed by k2 (after k1 done), used by k3 finalize
#define WS_SARR 16384    // 32768 : sv[t] = 2*(e[t]+mask[t])
#define WS_BMAX 49152    // 512   : per-k1-block online max
#define WS_BSUM 49664    // 512   : per-k1-block online sumexp
#define WS_SSUM 50178    // 1     : sum of clipped u
#define WS_CTR  50180    // 1     : uint finalize counter for k3 (zeroed by k0)
#define WS_U    50432    // 32768 : u[t]

__device__ __forceinline__ float fast_tanh(float x) {
    // tanh(x) = 1 - 2/(exp(2x)+1); ~1e-7 abs err vs 3.5e-4 threshold
    float e = __expf(2.0f * x);
    return 1.0f - 2.0f * __builtin_amdgcn_rcpf(e + 1.0f);
}

__device__ __forceinline__ float uniform_f(float v) {
    return __uint_as_float(__builtin_amdgcn_readfirstlane(__float_as_uint(v)));
}

// ---------------- K0: dec_proj+bias -> base[512]; G[31][512]; zero SSUM/CTR -----------
__global__ __launch_bounds__(256) void k0_prep(
        const float* __restrict__ dec_z, const float* __restrict__ conv_w,
        const float* __restrict__ conv_b, const float* __restrict__ W_att,
        const float* __restrict__ W_dec, float* __restrict__ ws) {
    int b = blockIdx.x, tid = threadIdx.x;
    int lane = tid & 63, wave = tid >> 6;
    if (b < 64) {
        // 8 a's per block, wave handles 2 (64-lane dot over 1024)
        for (int s = 0; s < 2; ++s) {
            int a = b * 8 + wave * 2 + s;
            float sum = 0.f;
            #pragma unroll
            for (int i = 0; i < 16; ++i)
                sum += W_dec[a * NDEC + i * 64 + lane] * dec_z[i * 64 + lane];
            #pragma unroll
            for (int off = 32; off > 0; off >>= 1) sum += __shfl_xor(sum, off);
            if (lane == 0) {
                float bias = 0.f;
                #pragma unroll
                for (int c = 0; c < 32; ++c) bias += conv_b[c] * W_att[a * 32 + c];
                ws[WS_BASE + a] = sum + bias;
            }
        }
    } else if (b < 64 + KTAPS) {
        int k = b - 64;
        for (int r = 0; r < 2; ++r) {
            int a = tid + r * 256;
            float g = 0.f;
            #pragma unroll
            for (int c = 0; c < 32; ++c) g += conv_w[c * KTAPS + k] * W_att[a * 32 + c];
            ws[WS_G + k * ADIM + a] = g;
        }
    } else {
        if (tid == 0) {
            ws[WS_SSUM] = 0.f;
            ((unsigned int*)ws)[WS_CTR] = 0u;
        }
    }
}

// ---------------- K1: sv[t]=2*(e[t]+mask[t]) + per-block online (max,sumexp) ----------
// 512 blocks x 512 thr (8 waves, bounds(512,4) -> 128-VGPR cap, NO spill — R5's
// (256,5)/96-cap spilled acc[]/p[] to scratch and regressed 5x). Wave w owns
// t = t0+8w..t0+8w+7; the two 256-wide a-halves sequential (float4 acc[8] = 32 VGPR).
__global__ __launch_bounds__(512, 4) void k1_energy(
        const float* __restrict__ att_prev, const float* __restrict__ pre,
        const float* __restrict__ mask, const float* __restrict__ W_g,
        const float* __restrict__ b_g, float* __restrict__ ws) {
    __shared__ float Gs[KTAPS * ADIM];   // 63488 B -> 2 blocks/CU = 16 waves/CU
    __shared__ float ap_s[96];
    __shared__ float wm[8], wz[8];
    int tid = threadIdx.x, lane = tid & 63, wave = tid >> 6;
    int t0 = blockIdx.x * 64;

    // stage G (15872 floats = 3968 float4)
    const float4* Gsrc = (const float4*)(ws + WS_G);
    float4* Gdst = (float4*)Gs;
    #pragma unroll
    for (int i = 0; i < 8; ++i) {
        int idx = tid + i * 512;
        if (idx < 3968) Gdst[idx] = Gsrc[idx];
    }
    if (tid < 94) {
        int g = t0 - 15 + tid;
        ap_s[tid] = (g >= 0 && g < T_LEN) ? att_prev[g] : 0.f;
    }
    __syncthreads();

    float bg = b_g[0];
    int tb_local = wave * 8;
    int tb = t0 + tb_local;

    // wave-uniform ap window -> SGPRs (zero VGPR cost)
    float ap_u[38];
    #pragma unroll
    for (int i = 0; i < 38; ++i) ap_u[i] = uniform_f(ap_s[tb_local + i]);

    float ps[8];
    #pragma unroll
    for (int j = 0; j < 8; ++j) ps[j] = 0.f;

    #pragma unroll 1
    for (int half = 0; half < 2; ++half) {
        int aa = half * 256 + 4 * lane;
        float4 base = *(const float4*)(ws + WS_BASE + aa);
        float4 wg   = *(const float4*)(W_g + aa);

        float4 p[8];
        #pragma unroll
        for (int j = 0; j < 8; ++j)
            p[j] = *(const float4*)(pre + (size_t)(tb + j) * ADIM + aa);

        float4 acc[8];
        #pragma unroll
        for (int j = 0; j < 8; ++j) acc[j] = base;

        #pragma unroll
        for (int k = 0; k < KTAPS; ++k) {
            float4 g = *(const float4*)(&Gs[k * ADIM + aa]);
            #pragma unroll
            for (int j = 0; j < 8; ++j) {
                float apv = ap_u[j + k];
                acc[j].x = fmaf(apv, g.x, acc[j].x);
                acc[j].y = fmaf(apv, g.y, acc[j].y);
                acc[j].z = fmaf(apv, g.z, acc[j].z);
                acc[j].w = fmaf(apv, g.w, acc[j].w);
            }
        }
        #pragma unroll
        for (int j = 0; j < 8; ++j) {
            float s = ps[j];
            s = fmaf(fast_tanh(p[j].x + acc[j].x), wg.x, s);
            s = fmaf(fast_tanh(p[j].y + acc[j].y), wg.y, s);
            s = fmaf(fast_tanh(p[j].z + acc[j].z), wg.z, s);
            s = fmaf(fast_tanh(p[j].w + acc[j].w), wg.w, s);
            ps[j] = s;
        }
    }

    float m_run = -1e30f, z_run = 0.f;
    #pragma unroll
    for (int j = 0; j < 8; ++j) {
        float e = ps[j];
        #pragma unroll
        for (int off = 32; off > 0; off >>= 1) e += __shfl_xor(e, off);
        int t = tb + j;
        float sv = 2.0f * (e + bg + mask[t]);
        float mn = fmaxf(m_run, sv);
        z_run = z_run * __expf(m_run - mn) + __expf(sv - mn);
        m_run = mn;
        if (lane == 0) ws[WS_SARR + t] = sv;
    }
    if (lane == 0) { wm[wave] = m_run; wz[wave] = z_run; }
    __syncthreads();
    if (tid == 0) {
        float M = wm[0], Z = wz[0];
        #pragma unroll
        for (int w = 1; w < 8; ++w) {
            float mn = fmaxf(M, wm[w]);
            Z = Z * __expf(M - mn) + wz[w] * __expf(wm[w] - mn);
            M = mn;
        }
        ws[WS_BMAX + blockIdx.x] = M;
        ws[WS_BSUM + blockIdx.x] = Z;
    }
}

// ---------------- K2: (M,Z) combine; u[t]; atomic S; zero c-replicas ------------------
__global__ __launch_bounds__(256) void k2_weights(
        const float* __restrict__ att_prev, float* __restrict__ ws) {
    __shared__ float sm[256], sz[256];
    __shared__ float wsum[4];
    int tid = threadIdx.x;
    // zero the 32 replicated c-accumulators (region aliases BASE+G — dead after k1):
    // 128 blocks x 128 floats = 16384 floats
    if (tid < 128) ws[WS_CREP + blockIdx.x * 128 + tid] = 0.f;

    float m1 = ws[WS_BMAX + tid],       z1 = ws[WS_BSUM + tid];
    float m2 = ws[WS_BMAX + tid + 256], z2 = ws[WS_BSUM + tid + 256];
    float M = fmaxf(m1, m2);
    float Z = z1 * __expf(m1 - M) + z2 * __expf(m2 - M);
    sm[tid] = M; sz[tid] = Z;
    __syncthreads();
    for (int s = 128; s > 0; s >>= 1) {
        if (tid < s) {
            float ma = sm[tid], mb = sm[tid + s];
            float mn = fmaxf(ma, mb);
            sz[tid] = sz[tid] * __expf(ma - mn) + sz[tid + s] * __expf(mb - mn);
            sm[tid] = mn;
        }
        __syncthreads();
    }
    M = sm[0];
    float invZ = 1.0f / sz[0];
    int t = blockIdx.x * 256 + tid;
    float pair = att_prev[t] + ((t > 0) ? att_prev[t - 1] : 0.f);
    float u = fmaxf(pair * __expf(ws[WS_SARR + t] - M) * invZ, 1e-6f);
    ws[WS_U + t] = u;
    float s = u;
    #pragma unroll
    for (int off = 32; off > 0; off >>= 1) s += __shfl_xor(s, off);
    int lane = tid & 63, wave = tid >> 6;
    if (lane == 0) wsum[wave] = s;
    __syncthreads();
    if (tid == 0) atomicAdd(&ws[WS_SSUM], wsum[0] + wsum[1] + wsum[2] + wsum[3]);
}

// ---------------- K3: w -> out[512+]; c partials -> 32 replicas; last block finalizes -
// 1024 blocks x 512 thr. 4 teams of 128; team covers 8 t's x 512 a's.
__global__ __launch_bounds__(512) void k3_context(
        const float* __restrict__ enc_h, float* __restrict__ ws,
        float* __restrict__ out) {
    __shared__ float cbuf[4 * 512];
    __shared__ int is_last;
    int tid = threadIdx.x;
    int team = tid >> 7, l = tid & 127;
    int a4 = 4 * l;
    int t0 = blockIdx.x * 32;
    float invS = 1.0f / ws[WS_SSUM];
    if (tid < 32) out[512 + t0 + tid] = ws[WS_U + t0 + tid] * invS;
    int tbase = t0 + team * 8;
    float4 acc = make_float4(0.f, 0.f, 0.f, 0.f);
    #pragma unroll
    for (int i = 0; i < 8; ++i) {
        int t = tbase + i;
        float wt = ws[WS_U + t] * invS;
        float4 e = *(const float4*)(enc_h + (size_t)t * ADIM + a4);
        acc.x = fmaf(wt, e.x, acc.x);
        acc.y = fmaf(wt, e.y, acc.y);
        acc.z = fmaf(wt, e.z, acc.z);
        acc.w = fmaf(wt, e.w, acc.w);
    }
    if (team != 0) *(float4*)&cbuf[team * 512 + a4] = acc;
    __syncthreads();
    if (team == 0) {
        float4 b1 = *(const float4*)&cbuf[1 * 512 + a4];
        float4 b2 = *(const float4*)&cbuf[2 * 512 + a4];
        float4 b3 = *(const float4*)&cbuf[3 * 512 + a4];
        float* rep = ws + WS_CREP + (blockIdx.x & 31) * 512;
        atomicAdd(&rep[a4 + 0], acc.x + b1.x + b2.x + b3.x);
        atomicAdd(&rep[a4 + 1], acc.y + b1.y + b2.y + b3.y);
        atomicAdd(&rep[a4 + 2], acc.z + b1.z + b2.z + b3.z);
        atomicAdd(&rep[a4 + 3], acc.w + b1.w + b2.w + b3.w);
        __threadfence();
    }
    __syncthreads();
    if (tid == 0) {
        unsigned int old = atomicAdd(&((unsigned int*)ws)[WS_CTR], 1u);
        is_last = (old == gridDim.x - 1);
    }
    __syncthreads();
    if (is_last) {
        __threadfence();
        float accf = 0.f;
        #pragma unroll
        for (int r = 0; r < 32; ++r) accf += ws[WS_CREP + r * 512 + tid];
        out[tid] = accf;
    }
}

extern "C" void kernel_launch(void* const* d_in, const int* in_sizes, int n_in,
                              void* d_out, int out_size, void* d_ws, size_t ws_size,
                              hipStream_t stream) {
    const float* dec_z    = (const float*)d_in[0];
    const float* att_prev = (const float*)d_in[1];
    const float* pre      = (const float*)d_in[2];
    const float* enc_h    = (const float*)d_in[3];
    const float* mask     = (const float*)d_in[4];
    const float* conv_w   = (const float*)d_in[5];
    const float* conv_b   = (const float*)d_in[6];
    const float* W_att    = (const float*)d_in[7];
    const float* W_dec    = (const float*)d_in[8];
    const float* W_g      = (const float*)d_in[9];
    const float* b_g      = (const float*)d_in[10];
    float* out = (float*)d_out;
    float* ws  = (float*)d_ws;

    k0_prep   <<<96,   256, 0, stream>>>(dec_z, conv_w, conv_b, W_att, W_dec, ws);
    k1_energy <<<512,  512, 0, stream>>>(att_prev, pre, mask, W_g, b_g, ws);
    k2_weights<<<128,  256, 0, stream>>>(att_prev, ws);
    k3_context<<<1024, 512, 0, stream>>>(enc_h, ws, out);
}

// Round 7
// 189.886 us; speedup vs baseline: 2.2780x; 1.4473x over previous
//
#include <hip/hip_runtime.h>

#define T_LEN 32768
#define ADIM  512
#define NDEC  1024
#define KTAPS 31

// workspace float offsets (no aliasing — ws is huge)
#define WS_BASE 0        // 512   : dec_proj[a] + conv-bias proj        (k0->k1)
#define WS_G    512      // 15872 : G[k][a] = sum_c conv_w[c,k]*W_att   (k0->k1)
#define WS_SARR 16384    // 32768 : sv[t] = 2*(e[t]+mask[t])            (k1->k3)
#define WS_BMAX 49152    // 512   : per-k1-block online max
#define WS_BSUM 49664    // 512   : per-k1-block online sumexp
#define WS_SSUM 50176    // 1     : S = sum of clipped u                (k3->k4)
#define WS_U    50432    // 32768 : unnormalized u[t]                   (k3->k4)
#define WS_CREP 83968    // 16384 : 32 replicated c~ accumulators (zeroed by k1 blocks 0..31)

__device__ __forceinline__ float fast_tanh(float x) {
    // tanh(x) = 1 - 2/(exp(2x)+1); ~1e-7 abs err vs 3.5e-4 threshold
    float e = __expf(2.0f * x);
    return 1.0f - 2.0f * __builtin_amdgcn_rcpf(e + 1.0f);
}

__device__ __forceinline__ float uniform_f(float v) {
    return __uint_as_float(__builtin_amdgcn_readfirstlane(__float_as_uint(v)));
}

// ---------------- K0: dec_proj+bias -> base[512]; G[31][512]; zero SSUM ---------------
__global__ __launch_bounds__(256) void k0_prep(
        const float* __restrict__ dec_z, const float* __restrict__ conv_w,
        const float* __restrict__ conv_b, const float* __restrict__ W_att,
        const float* __restrict__ W_dec, float* __restrict__ ws) {
    int b = blockIdx.x, tid = threadIdx.x;
    int lane = tid & 63, wave = tid >> 6;
    if (b < 64) {
        // 8 a's per block, wave handles 2 (64-lane dot over 1024)
        for (int s = 0; s < 2; ++s) {
            int a = b * 8 + wave * 2 + s;
            float sum = 0.f;
            #pragma unroll
            for (int i = 0; i < 16; ++i)
                sum += W_dec[a * NDEC + i * 64 + lane] * dec_z[i * 64 + lane];
            #pragma unroll
            for (int off = 32; off > 0; off >>= 1) sum += __shfl_xor(sum, off);
            if (lane == 0) {
                float bias = 0.f;
                #pragma unroll
                for (int c = 0; c < 32; ++c) bias += conv_b[c] * W_att[a * 32 + c];
                ws[WS_BASE + a] = sum + bias;
            }
        }
    } else if (b < 64 + KTAPS) {
        int k = b - 64;
        for (int r = 0; r < 2; ++r) {
            int a = tid + r * 256;
            float g = 0.f;
            #pragma unroll
            for (int c = 0; c < 32; ++c) g += conv_w[c * KTAPS + k] * W_att[a * 32 + c];
            ws[WS_G + k * ADIM + a] = g;
        }
    } else {
        if (tid == 0) ws[WS_SSUM] = 0.f;
    }
}

// ---------------- K1: sv[t]=2*(e[t]+mask[t]) + per-block online (max,sumexp) ----------
// 512 blocks x 512 thr (8 waves, bounds(512,4) -> 128-VGPR cap, NO spill — R5's
// (256,5)/96-cap spilled acc[]/p[] and regressed 5x; R1's unbounded 135-live set
// spilled too. This envelope is HW-proven). Wave w owns t=t0+8w..+7; the two 256-wide
// a-halves sequential (float4 acc[8] = 32 VGPR). Blocks 0..31 also zero the c-replicas.
__global__ __launch_bounds__(512, 4) void k1_energy(
        const float* __restrict__ att_prev, const float* __restrict__ pre,
        const float* __restrict__ mask, const float* __restrict__ W_g,
        const float* __restrict__ b_g, float* __restrict__ ws) {
    __shared__ float Gs[KTAPS * ADIM];   // 63488 B -> 2 blocks/CU = 16 waves/CU
    __shared__ float ap_s[96];
    __shared__ float wm[8], wz[8];
    int tid = threadIdx.x, lane = tid & 63, wave = tid >> 6;
    int t0 = blockIdx.x * 64;

    // zero c~ replicas for k3 (kernel boundary = the fence; NO __threadfence here —
    // R6's per-block device fence cost 115 us in k3)
    if (blockIdx.x < 32) ws[WS_CREP + blockIdx.x * 512 + tid] = 0.f;

    // stage G (15872 floats = 3968 float4)
    const float4* Gsrc = (const float4*)(ws + WS_G);
    float4* Gdst = (float4*)Gs;
    #pragma unroll
    for (int i = 0; i < 8; ++i) {
        int idx = tid + i * 512;
        if (idx < 3968) Gdst[idx] = Gsrc[idx];
    }
    if (tid < 94) {
        int g = t0 - 15 + tid;
        ap_s[tid] = (g >= 0 && g < T_LEN) ? att_prev[g] : 0.f;
    }
    __syncthreads();

    float bg = b_g[0];
    int tb_local = wave * 8;
    int tb = t0 + tb_local;

    // wave-uniform ap window -> SGPRs (zero VGPR cost)
    float ap_u[38];
    #pragma unroll
    for (int i = 0; i < 38; ++i) ap_u[i] = uniform_f(ap_s[tb_local + i]);

    float ps[8];
    #pragma unroll
    for (int j = 0; j < 8; ++j) ps[j] = 0.f;

    #pragma unroll 1
    for (int half = 0; half < 2; ++half) {
        int aa = half * 256 + 4 * lane;
        float4 base = *(const float4*)(ws + WS_BASE + aa);
        float4 wg   = *(const float4*)(W_g + aa);

        float4 p[8];
        #pragma unroll
        for (int j = 0; j < 8; ++j)
            p[j] = *(const float4*)(pre + (size_t)(tb + j) * ADIM + aa);

        float4 acc[8];
        #pragma unroll
        for (int j = 0; j < 8; ++j) acc[j] = base;

        #pragma unroll
        for (int k = 0; k < KTAPS; ++k) {
            float4 g = *(const float4*)(&Gs[k * ADIM + aa]);
            #pragma unroll
            for (int j = 0; j < 8; ++j) {
                float apv = ap_u[j + k];
                acc[j].x = fmaf(apv, g.x, acc[j].x);
                acc[j].y = fmaf(apv, g.y, acc[j].y);
                acc[j].z = fmaf(apv, g.z, acc[j].z);
                acc[j].w = fmaf(apv, g.w, acc[j].w);
            }
        }
        #pragma unroll
        for (int j = 0; j < 8; ++j) {
            float s = ps[j];
            s = fmaf(fast_tanh(p[j].x + acc[j].x), wg.x, s);
            s = fmaf(fast_tanh(p[j].y + acc[j].y), wg.y, s);
            s = fmaf(fast_tanh(p[j].z + acc[j].z), wg.z, s);
            s = fmaf(fast_tanh(p[j].w + acc[j].w), wg.w, s);
            ps[j] = s;
        }
    }

    float m_run = -1e30f, z_run = 0.f;
    #pragma unroll
    for (int j = 0; j < 8; ++j) {
        float e = ps[j];
        #pragma unroll
        for (int off = 32; off > 0; off >>= 1) e += __shfl_xor(e, off);
        int t = tb + j;
        float sv = 2.0f * (e + bg + mask[t]);
        float mn = fmaxf(m_run, sv);
        z_run = z_run * __expf(m_run - mn) + __expf(sv - mn);
        m_run = mn;
        if (lane == 0) ws[WS_SARR + t] = sv;
    }
    if (lane == 0) { wm[wave] = m_run; wz[wave] = z_run; }
    __syncthreads();
    if (tid == 0) {
        float M = wm[0], Z = wz[0];
        #pragma unroll
        for (int w = 1; w < 8; ++w) {
            float mn = fmaxf(M, wm[w]);
            Z = Z * __expf(M - mn) + wz[w] * __expf(wm[w] - mn);
            M = mn;
        }
        ws[WS_BMAX + blockIdx.x] = M;
        ws[WS_BSUM + blockIdx.x] = Z;
    }
}

// ---------------- K3: redundant (M,Z) combine; u[t]; c~ partials; S -------------------
// 1024 blocks x 512 thr. Prologue: 8 waves butterfly-combine the 512 (M,Z) pairs.
// 4 teams of 128; team covers 8 t's x 512 a's with unnormalized u; team-0 atomics
// into one of 32 replicas (no fence). Wave-0 lanes 0..31 write u[t] + atomic S.
__global__ __launch_bounds__(512) void k3_context(
        const float* __restrict__ att_prev, const float* __restrict__ enc_h,
        float* __restrict__ ws) {
    __shared__ float wmz[16];
    __shared__ float cbuf[4 * 512];
    int tid = threadIdx.x, lane = tid & 63, wave = tid >> 6;

    // combine 512 (M,Z) pairs: wave w owns chunk [64w, 64w+64)
    float m = ws[WS_BMAX + wave * 64 + lane];
    float z = ws[WS_BSUM + wave * 64 + lane];
    #pragma unroll
    for (int off = 32; off > 0; off >>= 1) {
        float mo = __shfl_xor(m, off), zo = __shfl_xor(z, off);
        float mn = fmaxf(m, mo);
        z = z * __expf(m - mn) + zo * __expf(mo - mn);
        m = mn;
    }
    if (lane == 0) { wmz[wave] = m; wmz[8 + wave] = z; }
    __syncthreads();
    float M = wmz[0], Z = wmz[8];
    #pragma unroll
    for (int w = 1; w < 8; ++w) {
        float mn = fmaxf(M, wmz[w]);
        Z = Z * __expf(M - mn) + wmz[8 + w] * __expf(wmz[w] - mn);
        M = mn;
    }
    float invZ = 1.0f / Z;

    int t0 = blockIdx.x * 32;
    int team = tid >> 7, l = tid & 127;
    int a4 = 4 * l;
    int tbase = t0 + team * 8;
    float4 acc = make_float4(0.f, 0.f, 0.f, 0.f);
    #pragma unroll
    for (int i = 0; i < 8; ++i) {
        int t = tbase + i;
        float ap0 = att_prev[t];
        float apm = (t > 0) ? att_prev[t - 1] : 0.f;
        float u = fmaxf((ap0 + apm) * __expf(ws[WS_SARR + t] - M) * invZ, 1e-6f);
        float4 e = *(const float4*)(enc_h + (size_t)t * ADIM + a4);
        acc.x = fmaf(u, e.x, acc.x);
        acc.y = fmaf(u, e.y, acc.y);
        acc.z = fmaf(u, e.z, acc.z);
        acc.w = fmaf(u, e.w, acc.w);
    }
    if (team != 0) *(float4*)&cbuf[team * 512 + a4] = acc;

    // wave 0, lanes 0..31: write unnormalized u[t] for this block + S partial
    if (tid < 32) {
        int t = t0 + tid;
        float ap0 = att_prev[t];
        float apm = (t > 0) ? att_prev[t - 1] : 0.f;
        float u = fmaxf((ap0 + apm) * __expf(ws[WS_SARR + t] - M) * invZ, 1e-6f);
        ws[WS_U + t] = u;
        float s = u;
        #pragma unroll
        for (int off = 16; off > 0; off >>= 1) s += __shfl_xor(s, off, 32);
        if (tid == 0) atomicAdd(&ws[WS_SSUM], s);
    }
    __syncthreads();
    if (team == 0) {
        float4 b1 = *(const float4*)&cbuf[1 * 512 + a4];
        float4 b2 = *(const float4*)&cbuf[2 * 512 + a4];
        float4 b3 = *(const float4*)&cbuf[3 * 512 + a4];
        float* rep = ws + WS_CREP + (blockIdx.x & 31) * 512;
        atomicAdd(&rep[a4 + 0], acc.x + b1.x + b2.x + b3.x);
        atomicAdd(&rep[a4 + 1], acc.y + b1.y + b2.y + b3.y);
        atomicAdd(&rep[a4 + 2], acc.z + b1.z + b2.z + b3.z);
        atomicAdd(&rep[a4 + 3], acc.w + b1.w + b2.w + b3.w);
    }
}

// ---------------- K4: c = (sum replicas)/S -> out[0:512]; w = u/S -> out[512:] --------
__global__ __launch_bounds__(512) void k4_final(
        const float* __restrict__ ws, float* __restrict__ out) {
    int b = blockIdx.x, tid = threadIdx.x;
    float invS = 1.0f / ws[WS_SSUM];
    if (b == 0) {
        float acc = 0.f;
        #pragma unroll
        for (int r = 0; r < 32; ++r) acc += ws[WS_CREP + r * 512 + tid];
        out[tid] = acc * invS;
    } else {
        int i = (b - 1) * 512 + tid;
        out[512 + i] = ws[WS_U + i] * invS;
    }
}

extern "C" void kernel_launch(void* const* d_in, const int* in_sizes, int n_in,
                              void* d_out, int out_size, void* d_ws, size_t ws_size,
                              hipStream_t stream) {
    const float* dec_z    = (const float*)d_in[0];
    const float* att_prev = (const float*)d_in[1];
    const float* pre      = (const float*)d_in[2];
    const float* enc_h    = (const float*)d_in[3];
    const float* mask     = (const float*)d_in[4];
    const float* conv_w   = (const float*)d_in[5];
    const float* conv_b   = (const float*)d_in[6];
    const float* W_att    = (const float*)d_in[7];
    const float* W_dec    = (const float*)d_in[8];
    const float* W_g      = (const float*)d_in[9];
    const float* b_g      = (const float*)d_in[10];
    float* out = (float*)d_out;
    float* ws  = (float*)d_ws;

    k0_prep   <<<96,   256, 0, stream>>>(dec_z, conv_w, conv_b, W_att, W_dec, ws);
    k1_energy <<<512,  512, 0, stream>>>(att_prev, pre, mask, W_g, b_g, ws);
    k3_context<<<1024, 512, 0, stream>>>(att_prev, enc_h, ws);
    k4_final  <<<65,   512, 0, stream>>>(ws, out);
}